// Round 1
// baseline (140.761 us; speedup 1.0000x reference)
//
#include <hip/hip_runtime.h>
#include <math.h>

#define HD 512
#define WD 512
#define NP 255          // patch grid = 255 x 255
#define LP (NP * NP)    // 65025 patches, divisible by 9
#define LK (LP / 9)     // 7225
#define BATCH 32

// One thread per (b, l) patch.
// Semantics replicate the reference's flat reshape (b,9,L)->(b,L,9):
//   kk = l / 7225  -> window offset (di,dj) = (kk/3, kk%3), FIXED for all 9 elems
//   k in 0..8: ll = 9*(l%7225)+k -> source patch (pi2,pj2)=(ll/255, ll%255)
//   pixel = (2*pi2+di, 2*pj2+dj)
// argmin/argmax of |a-c| with first-occurrence tie-break (strict compares),
// s = c[argmin] + c[argmax]; broadcast to output pixels of patch (l/255, l%255);
// row 511 / col 511 are zero (mask in reference).
__global__ __launch_bounds__(256) void dc_pool_kernel(
    const float* __restrict__ anchor,
    const float* __restrict__ pos,
    const float* __restrict__ neg,
    float* __restrict__ out0,
    float* __restrict__ out1)
{
    int idx = blockIdx.x * blockDim.x + threadIdx.x;
    if (idx >= BATCH * LP) return;
    int b = idx / LP;
    int l = idx - b * LP;

    int kk = l / LK;
    int r  = l - kk * LK;
    int di = kk / 3;
    int dj = kk - 3 * di;

    const size_t plane = (size_t)HD * WD;
    const float* A = anchor + (size_t)b * plane;
    const float* P = pos    + (size_t)b * plane;
    const float* N = neg    + (size_t)b * plane;

    float minvP = 0.f, maxvP = 0.f, mindP = INFINITY, maxdP = -INFINITY;
    float minvN = 0.f, maxvN = 0.f, mindN = INFINITY, maxdN = -INFINITY;

    int base = 9 * r;
    #pragma unroll
    for (int k = 0; k < 9; ++k) {
        int ll  = base + k;
        int pi2 = ll / NP;
        int pj2 = ll - pi2 * NP;
        int off = (2 * pi2 + di) * WD + (2 * pj2 + dj);
        float a = A[off];
        float p = P[off];
        float n = N[off];
        float dp = fabsf(a - p);
        float dn = fabsf(a - n);
        if (dp < mindP) { mindP = dp; minvP = p; }   // first-occurrence argmin
        if (dp > maxdP) { maxdP = dp; maxvP = p; }   // first-occurrence argmax
        if (dn < mindN) { mindN = dn; minvN = n; }
        if (dn > maxdN) { maxdN = dn; maxvN = n; }
    }
    float s0 = minvP + maxvP;
    float s1 = minvN + maxvN;

    int piy = l / NP;
    int pjx = l - piy * NP;
    int y0 = 2 * piy;
    int x0 = 2 * pjx;
    int ny = (piy == NP - 1) ? 3 : 2;
    int nx = (pjx == NP - 1) ? 3 : 2;

    float* O0 = out0 + (size_t)b * plane;
    float* O1 = out1 + (size_t)b * plane;

    for (int yy = 0; yy < ny; ++yy) {
        int row = (y0 + yy) * WD;
        for (int xx = 0; xx < nx; ++xx) {
            O0[row + x0 + xx] = s0;
            O1[row + x0 + xx] = s1;
        }
        if (pjx == NP - 1) {         // column 511 -> 0 for this thread's rows
            O0[row + WD - 1] = 0.0f;
            O1[row + WD - 1] = 0.0f;
        }
    }
    if (piy == NP - 1) {             // row 511 -> 0 for this thread's cols
        int row = (HD - 1) * WD;
        for (int xx = 0; xx < nx; ++xx) {
            O0[row + x0 + xx] = 0.0f;
            O1[row + x0 + xx] = 0.0f;
        }
        if (pjx == NP - 1) {         // corner (511,511)
            O0[row + WD - 1] = 0.0f;
            O1[row + WD - 1] = 0.0f;
        }
    }
}

extern "C" void kernel_launch(void* const* d_in, const int* in_sizes, int n_in,
                              void* d_out, int out_size, void* d_ws, size_t ws_size,
                              hipStream_t stream) {
    const float* anchor = (const float*)d_in[0];
    const float* pos    = (const float*)d_in[1];
    const float* neg    = (const float*)d_in[2];
    float* out0 = (float*)d_out;
    float* out1 = out0 + (size_t)BATCH * HD * WD;

    int total = BATCH * LP;
    int block = 256;
    int grid  = (total + block - 1) / block;
    dc_pool_kernel<<<grid, block, 0, stream>>>(anchor, pos, neg, out0, out1);
}

// Round 2
// 73.337 us; speedup vs baseline: 1.9194x; 1.9194x over previous
//
#include <hip/hip_runtime.h>
#include <math.h>

#define HD 512
#define WD 512
#define NP 255          // patch grid = 255 x 255
#define LP (NP * NP)    // 65025 patches
#define LK (LP / 9)     // 7225 patches per kk-group
#define BATCH 32
#define RB 256          // r's per block
#define NBLK ((LK + RB - 1) / RB)   // 29
#define SMAX (9 * RB)   // 2304 staged elements

// Semantics (reference's flat reshape (b,9,L)->(b,L,9)):
//   l = kk*7225 + r ; (di,dj) = (kk/3, kk%3) fixed for the 9-group
//   k in 0..8: ll = 9r+k -> pixel (2*(ll/255)+di, 2*(ll%255)+dj)
//   argmin/argmax |a-c| (first-occurrence), s = c[argmin]+c[argmax]
//   broadcast to 2x2 (3x3 at edges) block of patch (l/255, l%255); row/col 511 = 0.
//
// Block = (b, kk, 256 consecutive r). Stage the gathered stride-2 pixels into
// LDS indexed by flat ll-offset (coalesced: 8 lines per wave-load instead of
// 64 for the direct gather), compute from contiguous LDS, store float2/float4.
__global__ __launch_bounds__(256) void dc_pool_kernel(
    const float* __restrict__ anchor,
    const float* __restrict__ pos,
    const float* __restrict__ neg,
    float* __restrict__ out0,
    float* __restrict__ out1)
{
    __shared__ float lA[SMAX], lP[SMAX], lN[SMAX];

    int bid = blockIdx.x;
    int rb  = bid % NBLK;
    int t2  = bid / NBLK;
    int kk  = t2 % 9;
    int b   = t2 / 9;
    int di  = kk / 3;
    int dj  = kk - 3 * di;

    int r0     = rb * RB;
    int rcount = min(RB, LK - r0);
    int S      = 9 * rcount;
    int llb    = 9 * r0;

    const size_t plane = (size_t)HD * WD;
    const float* A = anchor + (size_t)b * plane;
    const float* P = pos    + (size_t)b * plane;
    const float* N = neg    + (size_t)b * plane;

    // --- stage: lds[t] = img[pixel(llb + t)] , coalesced stride-2 reads ---
    for (int t = threadIdx.x; t < S; t += 256) {
        int ll  = llb + t;
        int pi2 = ll / NP;
        int pj2 = ll - pi2 * NP;
        int off = (2 * pi2 + di) * WD + (2 * pj2 + dj);
        lA[t] = A[off];
        lP[t] = P[off];
        lN[t] = N[off];
    }
    __syncthreads();

    int tid = threadIdx.x;
    if (tid >= rcount) return;

    // --- reduce 9 contiguous LDS elements ---
    int base = 9 * tid;
    float minvP = 0.f, maxvP = 0.f, mindP = INFINITY, maxdP = -INFINITY;
    float minvN = 0.f, maxvN = 0.f, mindN = INFINITY, maxdN = -INFINITY;
    #pragma unroll
    for (int k = 0; k < 9; ++k) {
        float a = lA[base + k];
        float p = lP[base + k];
        float n = lN[base + k];
        float dp = fabsf(a - p);
        float dn = fabsf(a - n);
        if (dp < mindP) { mindP = dp; minvP = p; }   // first-occurrence argmin
        if (dp > maxdP) { maxdP = dp; maxvP = p; }   // first-occurrence argmax
        if (dn < mindN) { mindN = dn; minvN = n; }
        if (dn > maxdN) { maxdN = dn; maxvN = n; }
    }
    float s0 = minvP + maxvP;
    float s1 = minvN + maxvN;

    // --- scatter to output (coalesced: adjacent threads -> adjacent 2x2) ---
    int l   = kk * LK + r0 + tid;
    int piy = l / NP;
    int pjx = l - piy * NP;
    int y0  = 2 * piy;
    int x0  = 2 * pjx;
    bool right  = (pjx == NP - 1);
    bool bottom = (piy == NP - 1);
    int ny = bottom ? 3 : 2;

    float* O0 = out0 + (size_t)b * plane;
    float* O1 = out1 + (size_t)b * plane;

    for (int yy = 0; yy < ny; ++yy) {
        float* p0 = O0 + (size_t)(y0 + yy) * WD + x0;
        float* p1 = O1 + (size_t)(y0 + yy) * WD + x0;
        if (right) {    // cols 508,509,510 = s ; col 511 = 0 ; 16B-aligned
            *reinterpret_cast<float4*>(p0) = make_float4(s0, s0, s0, 0.f);
            *reinterpret_cast<float4*>(p1) = make_float4(s1, s1, s1, 0.f);
        } else {
            *reinterpret_cast<float2*>(p0) = make_float2(s0, s0);
            *reinterpret_cast<float2*>(p1) = make_float2(s1, s1);
        }
    }
    if (bottom) {       // row 511 = 0
        float* p0 = O0 + (size_t)(HD - 1) * WD + x0;
        float* p1 = O1 + (size_t)(HD - 1) * WD + x0;
        if (right) {
            *reinterpret_cast<float4*>(p0) = make_float4(0.f, 0.f, 0.f, 0.f);
            *reinterpret_cast<float4*>(p1) = make_float4(0.f, 0.f, 0.f, 0.f);
        } else {
            *reinterpret_cast<float2*>(p0) = make_float2(0.f, 0.f);
            *reinterpret_cast<float2*>(p1) = make_float2(0.f, 0.f);
        }
    }
}

extern "C" void kernel_launch(void* const* d_in, const int* in_sizes, int n_in,
                              void* d_out, int out_size, void* d_ws, size_t ws_size,
                              hipStream_t stream) {
    const float* anchor = (const float*)d_in[0];
    const float* pos    = (const float*)d_in[1];
    const float* neg    = (const float*)d_in[2];
    float* out0 = (float*)d_out;
    float* out1 = out0 + (size_t)BATCH * HD * WD;

    int grid = BATCH * 9 * NBLK;   // 32 * 9 * 29 = 8352 blocks
    dc_pool_kernel<<<grid, 256, 0, stream>>>(anchor, pos, neg, out0, out1);
}

// Round 3
// 43.748 us; speedup vs baseline: 3.2175x; 1.6764x over previous
//
#include <hip/hip_runtime.h>
#include <math.h>

#define HD 512
#define WD 512
#define NP 255          // patch grid = 255 x 255
#define LP (NP * NP)    // 65025 patches
#define LK (LP / 9)     // 7225 patches per kk-group
#define BATCH 32
#define RB 128                        // r's per block
#define NBLK ((LK + RB - 1) / RB)     // 57
#define NTHR 384                      // 3 dj-groups x 128 r
#define MAXROWS 6                     // max pi2 span for S=1152 ll values

// Semantics (reference's flat reshape (b,9,L)->(b,L,9)):
//   l = kk*7225 + r ; (di,dj) = (kk/3, kk%3) fixed within a 9-group
//   k in 0..8: ll = 9r+k -> pixel (2*(ll/255)+di, 2*(ll%255)+dj)
//   argmin/argmax |a-c| (first-occurrence), s = c[argmin]+c[argmax]
//   broadcast to 2x2 (3x3 at edges) block of patch (l/255, l%255); row/col 511 = 0.
//
// Block = (b, di, 128 consecutive r); computes all 3 dj in one pass.
// The union of cols over dj=0,1,2 is ALL cols -> stage full contiguous image
// rows (2*pi2+di) with float4 loads: 100% line utilization, one fetch per line.
__global__ __launch_bounds__(NTHR) void dc_pool_kernel(
    const float* __restrict__ anchor,
    const float* __restrict__ pos,
    const float* __restrict__ neg,
    float* __restrict__ out0,
    float* __restrict__ out1)
{
    __shared__ float lA[MAXROWS * WD], lP[MAXROWS * WD], lN[MAXROWS * WD];

    int bid = blockIdx.x;
    int rb  = bid % NBLK;
    int t2  = bid / NBLK;
    int di  = t2 % 3;
    int b   = t2 / 3;

    int r0     = rb * RB;
    int rcount = min(RB, LK - r0);
    int llb    = 9 * r0;
    int lle    = llb + 9 * rcount - 1;
    int pi2min = llb / NP;
    int pi2max = lle / NP;
    int rows   = pi2max - pi2min + 1;       // <= 6

    const size_t plane = (size_t)HD * WD;
    const float* A = anchor + (size_t)b * plane;
    const float* P = pos    + (size_t)b * plane;
    const float* N = neg    + (size_t)b * plane;

    // --- stage full rows 2*pi2+di, pi2 in [pi2min, pi2max], float4 ---
    int base_row = 2 * pi2min + di;
    int nf4 = rows * (WD / 4);              // float4s per tensor (<= 768)
    for (int f = threadIdx.x; f < nf4; f += NTHR) {
        int rr = f >> 7;                    // f / 128
        int cc = (f & 127) << 2;            // col (floats)
        int go = (base_row + 2 * rr) * WD + cc;
        int lo = rr * WD + cc;
        *reinterpret_cast<float4*>(&lA[lo]) = *reinterpret_cast<const float4*>(&A[go]);
        *reinterpret_cast<float4*>(&lP[lo]) = *reinterpret_cast<const float4*>(&P[go]);
        *reinterpret_cast<float4*>(&lN[lo]) = *reinterpret_cast<const float4*>(&N[go]);
    }
    __syncthreads();

    int t   = threadIdx.x;
    int dj  = t / RB;                       // 0..2
    int idx = t - dj * RB;                  // 0..127
    if (idx >= rcount) return;

    // --- reduce the 9-group from LDS ---
    int r    = r0 + idx;
    int ll0  = 9 * r;
    int pi2  = ll0 / NP;
    int pj2  = ll0 - pi2 * NP;
    float minvP = 0.f, maxvP = 0.f, mindP = INFINITY, maxdP = -INFINITY;
    float minvN = 0.f, maxvN = 0.f, mindN = INFINITY, maxdN = -INFINITY;
    #pragma unroll
    for (int k = 0; k < 9; ++k) {
        int lo = (pi2 - pi2min) * WD + 2 * pj2 + dj;
        float a = lA[lo];
        float p = lP[lo];
        float n = lN[lo];
        float dp = fabsf(a - p);
        float dn = fabsf(a - n);
        if (dp < mindP) { mindP = dp; minvP = p; }   // first-occurrence argmin
        if (dp > maxdP) { maxdP = dp; maxvP = p; }   // first-occurrence argmax
        if (dn < mindN) { mindN = dn; minvN = n; }
        if (dn > maxdN) { maxdN = dn; maxvN = n; }
        if (++pj2 == NP) { pj2 = 0; ++pi2; }
    }
    float s0 = minvP + maxvP;
    float s1 = minvN + maxvN;

    // --- scatter to output (adjacent idx -> adjacent 2x2 blocks) ---
    int kk  = 3 * di + dj;
    int l   = kk * LK + r;
    int piy = l / NP;
    int pjx = l - piy * NP;
    int y0  = 2 * piy;
    int x0  = 2 * pjx;
    bool right  = (pjx == NP - 1);
    bool bottom = (piy == NP - 1);
    int ny = bottom ? 3 : 2;

    float* O0 = out0 + (size_t)b * plane;
    float* O1 = out1 + (size_t)b * plane;

    for (int yy = 0; yy < ny; ++yy) {
        float* p0 = O0 + (size_t)(y0 + yy) * WD + x0;
        float* p1 = O1 + (size_t)(y0 + yy) * WD + x0;
        if (right) {    // cols 508,509,510 = s ; col 511 = 0
            *reinterpret_cast<float4*>(p0) = make_float4(s0, s0, s0, 0.f);
            *reinterpret_cast<float4*>(p1) = make_float4(s1, s1, s1, 0.f);
        } else {
            *reinterpret_cast<float2*>(p0) = make_float2(s0, s0);
            *reinterpret_cast<float2*>(p1) = make_float2(s1, s1);
        }
    }
    if (bottom) {       // row 511 = 0
        float* p0 = O0 + (size_t)(HD - 1) * WD + x0;
        float* p1 = O1 + (size_t)(HD - 1) * WD + x0;
        if (right) {
            *reinterpret_cast<float4*>(p0) = make_float4(0.f, 0.f, 0.f, 0.f);
            *reinterpret_cast<float4*>(p1) = make_float4(0.f, 0.f, 0.f, 0.f);
        } else {
            *reinterpret_cast<float2*>(p0) = make_float2(0.f, 0.f);
            *reinterpret_cast<float2*>(p1) = make_float2(0.f, 0.f);
        }
    }
}

extern "C" void kernel_launch(void* const* d_in, const int* in_sizes, int n_in,
                              void* d_out, int out_size, void* d_ws, size_t ws_size,
                              hipStream_t stream) {
    const float* anchor = (const float*)d_in[0];
    const float* pos    = (const float*)d_in[1];
    const float* neg    = (const float*)d_in[2];
    float* out0 = (float*)d_out;
    float* out1 = out0 + (size_t)BATCH * HD * WD;

    int grid = BATCH * 3 * NBLK;   // 32 * 3 * 57 = 5472 blocks
    dc_pool_kernel<<<grid, NTHR, 0, stream>>>(anchor, pos, neg, out0, out1);
}

// Round 4
// 42.440 us; speedup vs baseline: 3.3167x; 1.0308x over previous
//
#include <hip/hip_runtime.h>
#include <math.h>

#define HD 512
#define WD 512
#define NP 255          // patch grid = 255 x 255
#define LP (NP * NP)    // 65025 patches
#define LK (LP / 9)     // 7225 patches per kk-group
#define BATCH 32
#define RB 128                        // r's per block
#define NBLK ((LK + RB - 1) / RB)     // 57
#define NTHR 384                      // 3 dj-groups x 128 r
#define MAXROWS 6                     // max pi2 span for 1152 consecutive ll
#define PAR 256                       // floats per parity-array row

// Semantics (reference's flat reshape (b,9,L)->(b,L,9)):
//   l = kk*7225 + r ; (di,dj) = (kk/3, kk%3) fixed within a 9-group
//   k in 0..8: ll = 9r+k -> pixel (2*(ll/255)+di, 2*(ll%255)+dj)
//   argmin/argmax |a-c| (first-occurrence), s = c[argmin]+c[argmax]
//   broadcast to 2x2 (3x3 at edges) block of patch (l/255, l%255); row/col 511 = 0.
//
// Block = (b, di, 128 consecutive r); computes all 3 dj in one pass.
// Staging: full image rows (2*pi2+di) via float4 (100% line utilization),
// DE-INTERLEAVED by column parity into lE/lO so compute reads have lane
// stride 9 floats (gcd(9,32)=1 -> conflict-free) instead of 18 (4-way).
__global__ __launch_bounds__(NTHR) void dc_pool_kernel(
    const float* __restrict__ anchor,
    const float* __restrict__ pos,
    const float* __restrict__ neg,
    float* __restrict__ out0,
    float* __restrict__ out1)
{
    __shared__ float lAe[MAXROWS * PAR], lAo[MAXROWS * PAR];
    __shared__ float lPe[MAXROWS * PAR], lPo[MAXROWS * PAR];
    __shared__ float lNe[MAXROWS * PAR], lNo[MAXROWS * PAR];

    int bid = blockIdx.x;
    int rb  = bid % NBLK;
    int t2  = bid / NBLK;
    int di  = t2 % 3;
    int b   = t2 / 3;

    int r0     = rb * RB;
    int rcount = min(RB, LK - r0);
    int llb    = 9 * r0;
    int lle    = llb + 9 * rcount - 1;
    int pi2min = llb / NP;
    int pi2max = lle / NP;
    int rows   = pi2max - pi2min + 1;       // <= 6

    const size_t plane = (size_t)HD * WD;
    const float* A = anchor + (size_t)b * plane;
    const float* P = pos    + (size_t)b * plane;
    const float* N = neg    + (size_t)b * plane;

    // --- stage rows 2*pi2+di as float4, split even/odd cols into lE/lO ---
    int base_row = 2 * pi2min + di;
    int nf4 = rows * (WD / 4);              // float4s per tensor (<= 768)
    #pragma unroll 2
    for (int f = threadIdx.x; f < nf4; f += NTHR) {
        int rr = f >> 7;                    // row index 0..rows-1
        int c  = f & 127;                   // float4 index within row
        int go = (base_row + 2 * rr) * WD + 4 * c;
        int lo = rr * PAR + 2 * c;
        float4 va = *reinterpret_cast<const float4*>(&A[go]);
        float4 vp = *reinterpret_cast<const float4*>(&P[go]);
        float4 vn = *reinterpret_cast<const float4*>(&N[go]);
        *reinterpret_cast<float2*>(&lAe[lo]) = make_float2(va.x, va.z);
        *reinterpret_cast<float2*>(&lAo[lo]) = make_float2(va.y, va.w);
        *reinterpret_cast<float2*>(&lPe[lo]) = make_float2(vp.x, vp.z);
        *reinterpret_cast<float2*>(&lPo[lo]) = make_float2(vp.y, vp.w);
        *reinterpret_cast<float2*>(&lNe[lo]) = make_float2(vn.x, vn.z);
        *reinterpret_cast<float2*>(&lNo[lo]) = make_float2(vn.y, vn.w);
    }
    __syncthreads();

    int t   = threadIdx.x;
    int dj  = t / RB;                       // 0..2
    int idx = t - dj * RB;                  // 0..127
    if (idx >= rcount) return;

    // --- reduce the 9-group from parity LDS (lane stride 9 -> no conflicts) ---
    int r    = r0 + idx;
    int ll0  = 9 * r;
    int pi2  = ll0 / NP;
    int pj2  = ll0 - pi2 * NP;
    // dj 0,2 -> even cols ; dj 1 -> odd cols ; entry = pj2 (+1 for dj==2)
    const float* sA = (dj == 1) ? lAo : lAe;
    const float* sP = (dj == 1) ? lPo : lPe;
    const float* sN = (dj == 1) ? lNo : lNe;
    int base = (pi2 - pi2min) * PAR + pj2 + ((dj == 2) ? 1 : 0);
    int wrapk = NP - pj2;                   // k >= wrapk -> next image row (+1)

    float minvP = 0.f, maxvP = 0.f, mindP = INFINITY, maxdP = -INFINITY;
    float minvN = 0.f, maxvN = 0.f, mindN = INFINITY, maxdN = -INFINITY;
    #pragma unroll
    for (int k = 0; k < 9; ++k) {
        int lo = base + k + ((k >= wrapk) ? 1 : 0);
        float a = sA[lo];
        float p = sP[lo];
        float n = sN[lo];
        float dp = fabsf(a - p);
        float dn = fabsf(a - n);
        if (dp < mindP) { mindP = dp; minvP = p; }   // first-occurrence argmin
        if (dp > maxdP) { maxdP = dp; maxvP = p; }   // first-occurrence argmax
        if (dn < mindN) { mindN = dn; minvN = n; }
        if (dn > maxdN) { maxdN = dn; maxvN = n; }
    }
    float s0 = minvP + maxvP;
    float s1 = minvN + maxvN;

    // --- scatter to output (adjacent idx -> adjacent 2x2 blocks) ---
    int kk  = 3 * di + dj;
    int l   = kk * LK + r;
    int piy = l / NP;
    int pjx = l - piy * NP;
    int y0  = 2 * piy;
    int x0  = 2 * pjx;
    bool right  = (pjx == NP - 1);
    bool bottom = (piy == NP - 1);
    int ny = bottom ? 3 : 2;

    float* O0 = out0 + (size_t)b * plane;
    float* O1 = out1 + (size_t)b * plane;

    for (int yy = 0; yy < ny; ++yy) {
        float* p0 = O0 + (size_t)(y0 + yy) * WD + x0;
        float* p1 = O1 + (size_t)(y0 + yy) * WD + x0;
        if (right) {    // cols 508,509,510 = s ; col 511 = 0
            *reinterpret_cast<float4*>(p0) = make_float4(s0, s0, s0, 0.f);
            *reinterpret_cast<float4*>(p1) = make_float4(s1, s1, s1, 0.f);
        } else {
            *reinterpret_cast<float2*>(p0) = make_float2(s0, s0);
            *reinterpret_cast<float2*>(p1) = make_float2(s1, s1);
        }
    }
    if (bottom) {       // row 511 = 0
        float* p0 = O0 + (size_t)(HD - 1) * WD + x0;
        float* p1 = O1 + (size_t)(HD - 1) * WD + x0;
        if (right) {
            *reinterpret_cast<float4*>(p0) = make_float4(0.f, 0.f, 0.f, 0.f);
            *reinterpret_cast<float4*>(p1) = make_float4(0.f, 0.f, 0.f, 0.f);
        } else {
            *reinterpret_cast<float2*>(p0) = make_float2(0.f, 0.f);
            *reinterpret_cast<float2*>(p1) = make_float2(0.f, 0.f);
        }
    }
}

extern "C" void kernel_launch(void* const* d_in, const int* in_sizes, int n_in,
                              void* d_out, int out_size, void* d_ws, size_t ws_size,
                              hipStream_t stream) {
    const float* anchor = (const float*)d_in[0];
    const float* pos    = (const float*)d_in[1];
    const float* neg    = (const float*)d_in[2];
    float* out0 = (float*)d_out;
    float* out1 = out0 + (size_t)BATCH * HD * WD;

    int grid = BATCH * 3 * NBLK;   // 32 * 3 * 57 = 5472 blocks
    dc_pool_kernel<<<grid, NTHR, 0, stream>>>(anchor, pos, neg, out0, out1);
}